// Round 15
// baseline (79.918 us; speedup 1.0000x reference)
//
#include <hip/hip_runtime.h>
#include <hip/hip_bf16.h>

#define SDIM 192
#define S2 (SDIM*SDIM)        // 36864
#define S3 ((size_t)SDIM*S2)  // 7077888
#define NCH 5
#define RAD 4                 // window 9

// ---- KA: one d-slice, 8 output rows, full 192-w strip per block; W reads raw from L2 ----
#define STRH 8
#define RROW 16               // halo rows (8 + 2*4)
#define WSTR 96               // uint (bf16x2) stride per wf row
#define NSTRIP (SDIM/STRH)    // 24

// ---- KB: D-axis add/sub sliding window, uint2 (4 bf16) per thread, 1-wave blocks ----
#define KB_THR 64
#define KB_KBC 4                            // w-positions per thread (one uint2 = 4 bf16)
#define KB_POSB (S2/(KB_THR*KB_KBC))        // 144
#define KB_DCH 8
#define KB_NDC (SDIM/KB_DCH)                // 24
#define KB_GRID (KB_POSB*KB_NDC)            // 3456
#define NPART KB_GRID

typedef float v2f __attribute__((ext_vector_type(2)));

__device__ __forceinline__ unsigned packbf(float lo, float hi) {
    // scalar-cast pair -> compiler emits v_cvt_pk_bf16_f32
    __hip_bfloat162 h2 = __float22bfloat162_rn(make_float2(lo, hi));
    unsigned u; __builtin_memcpy(&u, &h2, 4); return u;
}
__device__ __forceinline__ float ulo(unsigned u) { return __uint_as_float(u << 16); }
__device__ __forceinline__ float uhi(unsigned u) { return __uint_as_float(u & 0xffff0000u); }

// ---------------- KA: W + H 9-tap (zero-padded) of the 5 product channels ----------------
__global__ __launch_bounds__(256) void ka_wh(const float* __restrict__ pred,
                                             const float* __restrict__ tgt,
                                             unsigned* __restrict__ BU) {
    const int b = blockIdx.x;              // d*NSTRIP + strip
    const int strip = b % NSTRIP;
    const int d = b / NSTRIP;
    const int h0 = strip * STRH;
    const size_t dbase = (size_t)d * S2;
    const int t = threadIdx.x;

    __shared__ unsigned wfU[NCH][RROW][WSTR];   // bf16x2 over w — 30.7 KB only

    const float4* tg4 = (const float4*)tgt;
    const float4* pr4 = (const float4*)pred;

    // W phase: 768 units = RROW rows x 48 col-units, 3 per thread.
    // Unit reads raw quads (cu-1, cu, cu+1) straight from global (L2-served halo),
    // zero-masked outside the volume (w<0 / w>=192 / h outside).
#pragma unroll
    for (int it = 0; it < 3; ++it) {
        const int u = t + 256 * it;            // exact cover 0..767
        const int row = u / 48, cu = u % 48;
        const int hh = h0 - RAD + row;
        const bool hok = (hh >= 0) && (hh < SDIM);
        const size_t rb4 = (dbase + (size_t)(hok ? hh : 0) * SDIM) >> 2;
        float4 qi[3], qj[3];
#pragma unroll
        for (int s = 0; s < 3; ++s) {
            const int q = cu - 1 + s;
            const bool ok = hok && (q >= 0) && (q < 48);
            if (ok) { qi[s] = tg4[rb4 + q]; qj[s] = pr4[rb4 + q]; }
            else {
                qi[s] = make_float4(0.f, 0.f, 0.f, 0.f);
                qj[s] = make_float4(0.f, 0.f, 0.f, 0.f);
            }
        }
        const float fi[12] = {qi[0].x, qi[0].y, qi[0].z, qi[0].w,
                              qi[1].x, qi[1].y, qi[1].z, qi[1].w,
                              qi[2].x, qi[2].y, qi[2].z, qi[2].w};
        const float fj[12] = {qj[0].x, qj[0].y, qj[0].z, qj[0].w,
                              qj[1].x, qj[1].y, qj[1].z, qj[1].w,
                              qj[2].x, qj[2].y, qj[2].z, qj[2].w};

#define W4(CH, EXPR) { \
        float pv[12]; \
        _Pragma("unroll") for (int k = 0; k < 12; ++k) pv[k] = (EXPR); \
        float s0 = 0.f; \
        _Pragma("unroll") for (int k = 0; k < 9; ++k) s0 += pv[k]; \
        const float s1 = s0 - pv[0] + pv[9]; \
        const float s2 = s1 - pv[1] + pv[10]; \
        const float s3 = s2 - pv[2] + pv[11]; \
        uint2 o; o.x = packbf(s0, s1); o.y = packbf(s2, s3); \
        *(uint2*)&wfU[CH][row][2 * cu] = o; }

        W4(0, fi[k])
        W4(1, fj[k])
        W4(2, fi[k] * fi[k])
        W4(3, fj[k] * fj[k])
        W4(4, fi[k] * fj[k])
#undef W4
    }
    __syncthreads();

    // H phase: thread owns a (channel, w-pair) column; packed lo/hi sliding 9-sum over h.
#pragma unroll
    for (int it = 0; it < 2; ++it) {
        const int col = t + 256 * it;          // 0..479 = c*96 + wp
        if (col < NCH * 96) {
            const int c = col / 96, wp = col % 96;
            v2f vh[RROW];
#pragma unroll
            for (int r = 0; r < RROW; ++r) {
                const unsigned v = wfU[c][r][wp];
                vh[r] = (v2f){ulo(v), uhi(v)};
            }
            v2f s = vh[0];
#pragma unroll
            for (int r = 1; r < 9; ++r) s += vh[r];
            unsigned* dst = BU + (size_t)c * (S3 / 2) + (dbase + (size_t)h0 * SDIM) / 2 + wp;
            dst[0] = packbf(s.x, s.y);
#pragma unroll
            for (int hr = 1; hr < STRH; ++hr) {
                s += vh[hr + 8] - vh[hr - 1];
                dst[hr * (SDIM / 2)] = packbf(s.x, s.y);
            }
        }
    }
}

// ---------------- KB: D-axis add/sub sliding window, uint2 loads, 1-wave blocks ----------------
#define SLICE2(s, OP) { const size_t sb = ((size_t)(s) * S2 + pos0) >> 2; \
    _Pragma("unroll") for (int c = 0; c < NCH; ++c) { \
        const uint2 v = B2[(size_t)c * (S3 >> 2) + sb]; \
        z[c][0] OP ulo(v.x); z[c][1] OP uhi(v.x); \
        z[c][2] OP ulo(v.y); z[c][3] OP uhi(v.y); } }

__global__ __launch_bounds__(KB_THR) void kb_d_cc(const unsigned* __restrict__ BU,
                                                  float* __restrict__ partials) {
    const int bid = blockIdx.x;
    const int dc = bid / KB_POSB;
    const int pb = bid % KB_POSB;
    const int d0 = dc * KB_DCH;
    const int pos0 = pb * (KB_THR * KB_KBC) + threadIdx.x * KB_KBC;
    const uint2* B2 = (const uint2*)BU;

    float z[NCH][KB_KBC];
#pragma unroll
    for (int c = 0; c < NCH; ++c)
#pragma unroll
        for (int i = 0; i < KB_KBC; ++i) z[c][i] = 0.f;

    // warm up: window for output d0 (slices d0-4..d0+4, zero-padded)
#pragma unroll
    for (int dd = -RAD; dd <= RAD; ++dd) {
        const int s = d0 + dd;
        if (s >= 0 && s < SDIM) SLICE2(s, +=)
    }

    const float inv = 1.0f / 729.0f;
    const float eps = 1.1920929e-07f;      // np.finfo(float32).eps
    float acc = 0.f;

#pragma unroll
    for (int k = 0; k < KB_DCH; ++k) {
        const int d = d0 + k;
#pragma unroll
        for (int i = 0; i < KB_KBC; ++i) {
            const float mu1 = z[0][i] * inv;
            const float mu2 = z[1][i] * inv;
            const float sg1 = z[2][i] * inv - mu1 * mu1;
            const float sg2 = z[3][i] * inv - mu2 * mu2;
            const float s12 = z[4][i] * inv - mu1 * mu2;
            acc += (s12 * s12) * __builtin_amdgcn_rcpf(sg1 * sg2 + eps);
        }
        const int da = d + RAD + 1;
        const int ds = d - RAD;
        if (da < SDIM) SLICE2(da, +=)
        if (ds >= 0)   SLICE2(ds, -=)
    }

    // single-wave deterministic shuffle reduction
#pragma unroll
    for (int off = 32; off > 0; off >>= 1)
        acc += __shfl_down(acc, off, 64);
    if (threadIdx.x == 0) partials[bid] = acc;
}

// ---------------- K4: final deterministic reduction ----------------
__global__ __launch_bounds__(256) void k4_finalize(const float* __restrict__ partials,
                                                   float* __restrict__ out) {
    __shared__ float sm[256];
    float s = 0.f;
    for (int i = threadIdx.x; i < NPART; i += 256) s += partials[i];
    sm[threadIdx.x] = s;
    __syncthreads();
#pragma unroll
    for (int o = 128; o > 0; o >>= 1) {
        if (threadIdx.x < o) sm[threadIdx.x] += sm[threadIdx.x + o];
        __syncthreads();
    }
    if (threadIdx.x == 0) out[0] = 1.0f - sm[0] / (float)((size_t)SDIM * S2);
}

extern "C" void kernel_launch(void* const* d_in, const int* in_sizes, int n_in,
                              void* d_out, int out_size, void* d_ws, size_t ws_size,
                              hipStream_t stream) {
    const float* pred = (const float*)d_in[0];
    const float* tgt  = (const float*)d_in[1];
    float* out = (float*)d_out;

    const size_t b_bytes = (size_t)NCH * S3 * sizeof(__hip_bfloat16);   // ~70.8 MB
    const size_t b_pad = (b_bytes + 255) & ~(size_t)255;

    unsigned* BU = (unsigned*)d_ws;
    float* partials = (float*)((char*)d_ws + b_pad);

    ka_wh<<<SDIM * NSTRIP, 256, 0, stream>>>(pred, tgt, BU);
    kb_d_cc<<<KB_GRID, KB_THR, 0, stream>>>(BU, partials);
    k4_finalize<<<1, 256, 0, stream>>>(partials, out);
}